// Round 5
// baseline (384.919 us; speedup 1.0000x reference)
//
#include <hip/hip_runtime.h>

// Pillar scatter, gather-formulated with per-row binning:
//   out[b, f, y, x] = sum of pillars[b,p,:] over active pillars p at (y,x).
// Output [4, 64, 512, 512] fp32 (268 MB), written exactly once (no memset).
//
// Pass 1 (bin): active pillars -> per-(b,y) row lists.
// Pass 2 (fill): block per (b,y) row. Stage pillar rows in LDS (stride 68:
//   16B-aligned for b128 reads), x->slot map via LDS CAS, merge duplicate
//   cells in LDS, then emit via f-quads: 4x ds_read_b128 + register transpose
//   + 4x nontemporal float4 stores per quad; all-empty x-quads (~91%) take a
//   zero-store path with no LDS reads at all.
// Pass 3 (fixup): atomicAdd the (normally zero) row-overflow entries.

#define NF 64
#define XS 512
#define YS 512
#define ROWCAP 64            // max pillars staged per (b,y) row; mean ~12
#define PSTRIDE 68           // prow stride: 68*4B = 272B, 16B-aligned, !=0 mod banks
#define OVCAP 16384

typedef float vf4 __attribute__((ext_vector_type(4)));

__global__ void __launch_bounds__(256) bin_pillars(
    const int* __restrict__ coord,
    const int* __restrict__ contains,
    int* __restrict__ rowcnt,
    int* __restrict__ rowlist,
    int* __restrict__ ovcnt,
    int* __restrict__ ovlist,
    int BP, int P) {
  int gid = blockIdx.x * 256 + threadIdx.x;
  if (gid >= BP) return;
  if (contains[gid] == 0) return;
  int y = coord[gid * 3 + 1];
  int x = coord[gid * 3 + 2];
  int b = gid / P;
  int by = (b << 9) | y;
  int k = atomicAdd(rowcnt + by, 1);
  if (k < ROWCAP) {
    rowlist[by * ROWCAP + k] = (x << 16) | gid;   // gid < 48000 fits 16 bits
  } else {
    int o = atomicAdd(ovcnt, 1);
    if (o < OVCAP) ovlist[o] = gid;
  }
}

__global__ void __launch_bounds__(256) fill_out(
    const float* __restrict__ pillars,
    const int* __restrict__ rowcnt,
    const int* __restrict__ rowlist,
    float* __restrict__ out) {
  int by = blockIdx.x;            // [0, B*YS)
  int b = by >> 9;
  int y = by & 511;
  __shared__ int xmap[XS];                    // x -> staged row idx, or -1
  __shared__ float prow[ROWCAP * PSTRIDE];    // staged pillar rows

  int t = threadIdx.x;
  xmap[t] = -1;
  xmap[t + 256] = -1;
  __syncthreads();

  int n = rowcnt[by];
  if (n > ROWCAP) n = ROWCAP;

  // claim cells; CAS losers are duplicate-cell pillars -> merged below
  int myold = -1;
  if (t < n) {
    int e = rowlist[by * ROWCAP + t];
    int x = e >> 16;
    myold = atomicCAS(&xmap[x], -1, t);    // >=0: index of winning pillar
  }
  __syncthreads();

  // stage pillar rows (coalesced 256B loads per row; 2-way LDS write = free)
  int grp = t >> 6, lane = t & 63;
  for (int k = grp; k < n; k += 4) {
    int g = rowlist[by * ROWCAP + k] & 0xFFFF;
    prow[k * PSTRIDE + lane] = pillars[((size_t)g << 6) + lane];
  }
  __syncthreads();

  // merge duplicate cells into the winner's staged row (rare: ~0.13/row)
  if (myold >= 0) {
    for (int f = 0; f < NF; ++f)
      atomicAdd(&prow[myold * PSTRIDE + f], prow[t * PSTRIDE + f]);
  }
  __syncthreads();

  // emit: thread = (x-quad, f-quad-phase). 128 x-quads x 2 f-phases.
  int x4  = (t & 127) << 2;
  int fq0 = (t >> 7) << 2;                  // 0 or 4
  int4 s = *(const int4*)&xmap[x4];         // 16B-aligned LDS read
  size_t outbase = (((size_t)(b * NF)) << 18) + ((size_t)y << 9) + (size_t)x4;

  if ((s.x & s.y & s.z & s.w) < 0) {
    // all four cells empty (-1): pure zero fill, zero LDS traffic
    vf4 z = {0.f, 0.f, 0.f, 0.f};
#pragma unroll
    for (int fi = 0; fi < 8; ++fi) {
      int f = fi * 8 + fq0;
#pragma unroll
      for (int j = 0; j < 4; ++j)
        __builtin_nontemporal_store(z, (vf4*)(out + outbase + ((size_t)(f + j) << 18)));
    }
  } else {
    bool m0 = s.x >= 0, m1 = s.y >= 0, m2 = s.z >= 0, m3 = s.w >= 0;
    int o0 = (m0 ? s.x : 0) * PSTRIDE;
    int o1 = (m1 ? s.y : 0) * PSTRIDE;
    int o2 = (m2 ? s.z : 0) * PSTRIDE;
    int o3 = (m3 ? s.w : 0) * PSTRIDE;
    vf4 z = {0.f, 0.f, 0.f, 0.f};
#pragma unroll
    for (int fi = 0; fi < 8; ++fi) {
      int f = fi * 8 + fq0;
      vf4 r0 = *(const vf4*)&prow[o0 + f]; if (!m0) r0 = z;
      vf4 r1 = *(const vf4*)&prow[o1 + f]; if (!m1) r1 = z;
      vf4 r2 = *(const vf4*)&prow[o2 + f]; if (!m2) r2 = z;
      vf4 r3 = *(const vf4*)&prow[o3 + f]; if (!m3) r3 = z;
#pragma unroll
      for (int j = 0; j < 4; ++j) {
        vf4 v = {r0[j], r1[j], r2[j], r3[j]};   // register transpose
        __builtin_nontemporal_store(v, (vf4*)(out + outbase + ((size_t)(f + j) << 18)));
      }
    }
  }
}

__global__ void __launch_bounds__(256) fixup_overflow(
    const float* __restrict__ pillars,
    const int* __restrict__ coord,
    const int* __restrict__ ovlist,
    const int* __restrict__ ovcnt,
    float* __restrict__ out,
    int P) {
  int gid = blockIdx.x * 256 + threadIdx.x;
  int w = gid >> 6;
  int lane = gid & 63;
  int n = *ovcnt;
  if (n > OVCAP) n = OVCAP;
  int nw = gridDim.x * 4;
  for (int i = w; i < n; i += nw) {
    int g = ovlist[i];
    int y = coord[g * 3 + 1];
    int x = coord[g * 3 + 2];
    int b = g / P;
    atomicAdd(out + (((size_t)(b * NF + lane)) << 18) + ((size_t)y << 9) + x,
              pillars[((size_t)g << 6) + lane]);
  }
}

extern "C" void kernel_launch(void* const* d_in, const int* in_sizes, int n_in,
                              void* d_out, int out_size, void* d_ws, size_t ws_size,
                              hipStream_t stream) {
  const float* pillars  = (const float*)d_in[0];
  const int*   coord    = (const int*)d_in[1];
  const int*   contains = (const int*)d_in[2];
  float* out = (float*)d_out;

  const int BP = in_sizes[2];                    // B * P = 48000
  const int B  = out_size / (NF * XS * YS);      // 4
  const int P  = BP / B;                         // 12000
  const int NROW = B * YS;                       // 2048

  // workspace layout: [rowcnt 2048 ints][ovcnt 1 int + pad][rowlist][ovlist]
  int* rowcnt  = (int*)d_ws;
  int* ovcnt   = rowcnt + NROW;
  int* rowlist = ovcnt + 4;
  int* ovlist  = rowlist + NROW * ROWCAP;

  (void)hipMemsetAsync(rowcnt, 0, (size_t)(NROW + 4) * sizeof(int), stream);

  bin_pillars<<<(BP + 255) / 256, 256, 0, stream>>>(coord, contains, rowcnt,
                                                    rowlist, ovcnt, ovlist, BP, P);
  fill_out<<<NROW, 256, 0, stream>>>(pillars, rowcnt, rowlist, out);
  fixup_overflow<<<64, 256, 0, stream>>>(pillars, coord, ovlist, ovcnt, out, P);
}

// Round 6
// 292.535 us; speedup vs baseline: 1.3158x; 1.3158x over previous
//
#include <hip/hip_runtime.h>

// Pillar scatter, gather-formulated with per-row binning:
//   out[b, f, y, x] = sum of pillars[b,p,:] over active pillars p at (y,x).
// Output [4, 64, 512, 512] fp32 (268 MB), written exactly once (no memset).
//
// Pass 1 (bin): active pillars -> per-(b,y) row lists.
// Pass 2 (fill): block per (b,y) row. Stage pillar rows in LDS (stride 68:
//   16B-aligned for b128 reads), x->slot map via LDS CAS, merge duplicate
//   cells in LDS, then emit BRANCH-FREE: per f-quad, 4x ds_read_b128 (empty
//   cells read prow[0] = same-address broadcast) + cndmask-select zero +
//   register transpose + 4 dense nontemporal float4 stores. No divergent
//   store streams (R5's masked split caused partial-sector RMW: +90us).
// Pass 3 (fixup): atomicAdd the (normally zero) row-overflow entries.

#define NF 64
#define XS 512
#define YS 512
#define ROWCAP 64            // max pillars staged per (b,y) row; mean ~12
#define PSTRIDE 68           // prow stride: 272B, 16B-aligned, breaks pow2 banks
#define OVCAP 16384

typedef float vf4 __attribute__((ext_vector_type(4)));

__global__ void __launch_bounds__(256) bin_pillars(
    const int* __restrict__ coord,
    const int* __restrict__ contains,
    int* __restrict__ rowcnt,
    int* __restrict__ rowlist,
    int* __restrict__ ovcnt,
    int* __restrict__ ovlist,
    int BP, int P) {
  int gid = blockIdx.x * 256 + threadIdx.x;
  if (gid >= BP) return;
  if (contains[gid] == 0) return;
  int y = coord[gid * 3 + 1];
  int x = coord[gid * 3 + 2];
  int b = gid / P;
  int by = (b << 9) | y;
  int k = atomicAdd(rowcnt + by, 1);
  if (k < ROWCAP) {
    rowlist[by * ROWCAP + k] = (x << 16) | gid;   // gid < 48000 fits 16 bits
  } else {
    int o = atomicAdd(ovcnt, 1);
    if (o < OVCAP) ovlist[o] = gid;
  }
}

__global__ void __launch_bounds__(256) fill_out(
    const float* __restrict__ pillars,
    const int* __restrict__ rowcnt,
    const int* __restrict__ rowlist,
    float* __restrict__ out) {
  int by = blockIdx.x;            // [0, B*YS)
  int b = by >> 9;
  int y = by & 511;
  __shared__ int xmap[XS];                    // x -> staged row idx, or -1
  __shared__ float prow[ROWCAP * PSTRIDE];    // staged pillar rows

  int t = threadIdx.x;
  xmap[t] = -1;
  xmap[t + 256] = -1;
  __syncthreads();

  int n = rowcnt[by];
  if (n > ROWCAP) n = ROWCAP;

  // claim cells; CAS losers are duplicate-cell pillars -> merged below
  int myold = -1;
  if (t < n) {
    int e = rowlist[by * ROWCAP + t];
    int x = e >> 16;
    myold = atomicCAS(&xmap[x], -1, t);    // >=0: index of winning pillar
  }
  __syncthreads();

  // stage pillar rows (coalesced 256B loads per row; 2-way LDS write = free)
  int grp = t >> 6, lane = t & 63;
  for (int k = grp; k < n; k += 4) {
    int g = rowlist[by * ROWCAP + k] & 0xFFFF;
    prow[k * PSTRIDE + lane] = pillars[((size_t)g << 6) + lane];
  }
  __syncthreads();

  // merge duplicate cells into the winner's staged row (rare: ~0.13/row)
  if (myold >= 0) {
    for (int f = 0; f < NF; ++f)
      atomicAdd(&prow[myold * PSTRIDE + f], prow[t * PSTRIDE + f]);
  }
  __syncthreads();

  // emit: thread = (x-quad, f-quad-phase); branch-free, dense stores.
  int x4  = (t & 127) << 2;
  int fq0 = (t >> 7) << 2;                  // 0 or 4
  int4 s = *(const int4*)&xmap[x4];         // 16B-aligned LDS read
  bool m0 = s.x >= 0, m1 = s.y >= 0, m2 = s.z >= 0, m3 = s.w >= 0;
  int o0 = (m0 ? s.x : 0) * PSTRIDE;        // empty -> prow[0] (broadcast read)
  int o1 = (m1 ? s.y : 0) * PSTRIDE;
  int o2 = (m2 ? s.z : 0) * PSTRIDE;
  int o3 = (m3 ? s.w : 0) * PSTRIDE;
  size_t outbase = (((size_t)(b * NF)) << 18) + ((size_t)y << 9) + (size_t)x4;
  vf4 z = {0.f, 0.f, 0.f, 0.f};
#pragma unroll
  for (int fi = 0; fi < 8; ++fi) {
    int f = fi * 8 + fq0;
    vf4 r0 = *(const vf4*)&prow[o0 + f]; if (!m0) r0 = z;
    vf4 r1 = *(const vf4*)&prow[o1 + f]; if (!m1) r1 = z;
    vf4 r2 = *(const vf4*)&prow[o2 + f]; if (!m2) r2 = z;
    vf4 r3 = *(const vf4*)&prow[o3 + f]; if (!m3) r3 = z;
#pragma unroll
    for (int j = 0; j < 4; ++j) {
      vf4 v = {r0[j], r1[j], r2[j], r3[j]};   // register transpose
      __builtin_nontemporal_store(v, (vf4*)(out + outbase + ((size_t)(f + j) << 18)));
    }
  }
}

__global__ void __launch_bounds__(256) fixup_overflow(
    const float* __restrict__ pillars,
    const int* __restrict__ coord,
    const int* __restrict__ ovlist,
    const int* __restrict__ ovcnt,
    float* __restrict__ out,
    int P) {
  int gid = blockIdx.x * 256 + threadIdx.x;
  int w = gid >> 6;
  int lane = gid & 63;
  int n = *ovcnt;
  if (n > OVCAP) n = OVCAP;
  int nw = gridDim.x * 4;
  for (int i = w; i < n; i += nw) {
    int g = ovlist[i];
    int y = coord[g * 3 + 1];
    int x = coord[g * 3 + 2];
    int b = g / P;
    atomicAdd(out + (((size_t)(b * NF + lane)) << 18) + ((size_t)y << 9) + x,
              pillars[((size_t)g << 6) + lane]);
  }
}

extern "C" void kernel_launch(void* const* d_in, const int* in_sizes, int n_in,
                              void* d_out, int out_size, void* d_ws, size_t ws_size,
                              hipStream_t stream) {
  const float* pillars  = (const float*)d_in[0];
  const int*   coord    = (const int*)d_in[1];
  const int*   contains = (const int*)d_in[2];
  float* out = (float*)d_out;

  const int BP = in_sizes[2];                    // B * P = 48000
  const int B  = out_size / (NF * XS * YS);      // 4
  const int P  = BP / B;                         // 12000
  const int NROW = B * YS;                       // 2048

  // workspace layout: [rowcnt 2048 ints][ovcnt 1 int + pad][rowlist][ovlist]
  int* rowcnt  = (int*)d_ws;
  int* ovcnt   = rowcnt + NROW;
  int* rowlist = ovcnt + 4;
  int* ovlist  = rowlist + NROW * ROWCAP;

  (void)hipMemsetAsync(rowcnt, 0, (size_t)(NROW + 4) * sizeof(int), stream);

  bin_pillars<<<(BP + 255) / 256, 256, 0, stream>>>(coord, contains, rowcnt,
                                                    rowlist, ovcnt, ovlist, BP, P);
  fill_out<<<NROW, 256, 0, stream>>>(pillars, rowcnt, rowlist, out);
  fixup_overflow<<<64, 256, 0, stream>>>(pillars, coord, ovlist, ovcnt, out, P);
}